// Round 5
// baseline (319.954 us; speedup 1.0000x reference)
//
#include <hip/hip_runtime.h>
#include <hip/hip_bf16.h>
#include <math.h>

// Problem constants
#define C_DIM 256
#define BD    128   // B*D
#define HW    784   // H*W = K
#define CN    128
#define KPAD  800   // K padded to 25 tiles of 32 (pad = zeros)

typedef short bf16x8 __attribute__((ext_vector_type(8)));
typedef float f32x4 __attribute__((ext_vector_type(4)));

// fp32 -> bf16 RNE
__device__ inline ushort f2b(float f) {
  unsigned u = __float_as_uint(f);
  unsigned r = (u + 0x7FFFu + ((u >> 16) & 1u)) >> 16;
  return (ushort)r;
}

// ---------------------------------------------------------------------------
// K1: LayerNorm over C + transpose -> bf16 x_re [C][BD][KPAD] + row norms.
// grid (25, 128), block 256. Quad-row: each 16-lane quad owns one hw row;
// Σx and Σx² reduced in parallel (one 4-step shuffle phase). hw-tile 32
// (block 24: 16 rows + 16 zero-pad cols). LDS [c][36] = 18.4 KB -> 7 blk/CU.
// Write-out: ushort4 per lane, 8 stores per wave.
// ---------------------------------------------------------------------------
__global__ __launch_bounds__(256) void ln_transpose_kernel(
    const float* __restrict__ x, const float* __restrict__ lnw,
    const float* __restrict__ lnb, ushort* __restrict__ xre,
    float* __restrict__ anorm) {
  __shared__ ushort btile[256 * 36];   // [c][hw_local], stride 36 (72B, 8B-aligned)
  __shared__ float nbuf[4][256];
  const int t = threadIdx.x, bd = blockIdx.y, bx = blockIdx.x;
  const int hw0 = bx * 32;
  const int w = t >> 6, lane = t & 63;
  const int q = lane >> 4, l = lane & 15;
  const bool last = (bx == 24);
  const int ngroups = last ? 1 : 2;     // row-groups per wave
  const int rpw = ngroups * 4;          // rows per wave
  if (last) {  // zero pad rows r=16..31 (-> k = 784..799)
    for (int r = 16; r < 32; ++r) btile[t * 36 + r] = 0;
  }
  float4 wv[4], bv[4];
  for (int s = 0; s < 4; ++s) {
    wv[s] = *(const float4*)(lnw + s * 64 + l * 4);
    bv[s] = *(const float4*)(lnb + s * 64 + l * 4);
  }
  float nrm[4][4];
  for (int s = 0; s < 4; ++s)
    for (int j = 0; j < 4; ++j) nrm[s][j] = 0.f;
  const float* xb = x + ((size_t)bd * HW + hw0) * 256 + l * 4;
  for (int g = 0; g < ngroups; ++g) {
    int r = w * rpw + g * 4 + q;        // block-local row
    float4 v[4];
    for (int s = 0; s < 4; ++s)
      v[s] = *(const float4*)(xb + (size_t)r * 256 + s * 64);
    float sum = 0.f, sq = 0.f;
    for (int s = 0; s < 4; ++s) {
      sum += v[s].x + v[s].y + v[s].z + v[s].w;
      sq = fmaf(v[s].x, v[s].x, sq); sq = fmaf(v[s].y, v[s].y, sq);
      sq = fmaf(v[s].z, v[s].z, sq); sq = fmaf(v[s].w, v[s].w, sq);
    }
    for (int off = 1; off <= 8; off <<= 1) {  // two independent chains
      sum += __shfl_xor(sum, off, 64);
      sq  += __shfl_xor(sq, off, 64);
    }
    float mu = sum * (1.f / 256.f);
    float var = fmaf(-mu, mu, sq * (1.f / 256.f));
    float sc = rsqrtf(var + 1e-5f);
    for (int s = 0; s < 4; ++s) {
      float y0 = (v[s].x - mu) * sc * wv[s].x + bv[s].x;
      float y1 = (v[s].y - mu) * sc * wv[s].y + bv[s].y;
      float y2 = (v[s].z - mu) * sc * wv[s].z + bv[s].z;
      float y3 = (v[s].w - mu) * sc * wv[s].w + bv[s].w;
      nrm[s][0] = fmaf(y0, y0, nrm[s][0]);
      nrm[s][1] = fmaf(y1, y1, nrm[s][1]);
      nrm[s][2] = fmaf(y2, y2, nrm[s][2]);
      nrm[s][3] = fmaf(y3, y3, nrm[s][3]);
      int c = s * 64 + l * 4;
      btile[(c + 0) * 36 + r] = f2b(y0);
      btile[(c + 1) * 36 + r] = f2b(y1);
      btile[(c + 2) * 36 + r] = f2b(y2);
      btile[(c + 3) * 36 + r] = f2b(y3);
    }
  }
  // reduce norms over the 4 quads, q==0 publishes
  for (int s = 0; s < 4; ++s)
    for (int j = 0; j < 4; ++j) {
      float v = nrm[s][j];
      v += __shfl_xor(v, 16, 64);
      v += __shfl_xor(v, 32, 64);
      nrm[s][j] = v;
    }
  if (q == 0)
    for (int s = 0; s < 4; ++s)
      for (int j = 0; j < 4; ++j) nbuf[w][s * 64 + l * 4 + j] = nrm[s][j];
  __syncthreads();
  float tot = nbuf[0][t] + nbuf[1][t] + nbuf[2][t] + nbuf[3][t];
  atomicAdd(&anorm[t * 128 + bd], tot);  // anorm[c][bd]
  // write-out: ushort4/lane; 8-lane group per c-row (64 B), 8 c per instr
  for (int i = 0; i < 8; ++i) {
    int c = w * 64 + i * 8 + (lane >> 3);
    int ho = (lane & 7) * 4;
    ushort4 val = *(const ushort4*)&btile[c * 36 + ho];
    *(ushort4*)(xre + (size_t)c * (BD * KPAD) + (size_t)bd * KPAD + hw0 + ho) = val;
  }
}

// ---------------------------------------------------------------------------
// K2: cc fp32 -> bf16 [C][CN][KPAD] + fp32 row norms + zero K-pad.
// grid 2048, block 256. Quad-row: quad owns one row (196 float4, 13 iters),
// 4 rows per wave in parallel; 4-step quad shuffle for the norm.
// ---------------------------------------------------------------------------
__global__ __launch_bounds__(256) void cc_convert_kernel(
    const float* __restrict__ cc, ushort* __restrict__ ccb,
    float* __restrict__ bnorm) {
  int b = blockIdx.x, c = b >> 3;
  int t = threadIdx.x, w = t >> 6, lane = t & 63;
  int q = lane >> 4, l = lane & 15;
  int r = (b & 7) * 16 + w * 4 + q;
  const float4* src = (const float4*)(cc + ((size_t)c * CN + r) * HW);
  ushort* dst = ccb + ((size_t)c * CN + r) * KPAD;
  float nrm = 0.f;
  for (int i = 0; i < 13; ++i) {
    int f = i * 16 + l;
    if (f < 196) {
      float4 v = src[f];
      nrm = fmaf(v.x, v.x, nrm); nrm = fmaf(v.y, v.y, nrm);
      nrm = fmaf(v.z, v.z, nrm); nrm = fmaf(v.w, v.w, nrm);
      ushort4 o; o.x = f2b(v.x); o.y = f2b(v.y); o.z = f2b(v.z); o.w = f2b(v.w);
      *(ushort4*)(dst + f * 4) = o;
    }
  }
  for (int off = 1; off <= 8; off <<= 1) nrm += __shfl_xor(nrm, off, 64);
  if (l == 0) bnorm[c * 128 + r] = nrm;
  if (l < 4) *(ushort4*)(dst + 784 + l * 4) = make_ushort4(0, 0, 0, 0);
}

// ---------------------------------------------------------------------------
// K3: MFMA GEMM-dist. grid 512: c = bx>>1, mode = bx&1 (modes adjacent for
// L2 reuse of cc_b[c]). 128x128 tile, BK=32, 16x16x32 bf16 MFMA.
// Single-barrier double-buffered K-loop: issue tile k+1 after the barrier,
// compute tile k from the other buffer (barrier's vmcnt drain lands one full
// compute-phase later). mode1 (cc vs cc): A=B -> stage one tile, feed both
// MFMA operands from it. XOR chunk swizzle: chunk(row,q) at row*4+(q^(row&3)).
// ---------------------------------------------------------------------------
__global__ __launch_bounds__(256, 2) void gemm_mfma_kernel(
    const ushort* __restrict__ xre, const ushort* __restrict__ ccb,
    const float* __restrict__ anorm, const float* __restrict__ bnorm,
    float* __restrict__ out_d, float* __restrict__ out_s,
    float* __restrict__ out_c) {
  __shared__ __align__(16) ushort At[2][4096];  // 128 rows x 32 bf16 per buf
  __shared__ __align__(16) ushort Bt[2][4096];
  __shared__ float smin[2][128];
  __shared__ float ssum[2][128];
  const int bx = blockIdx.x;
  const int c = bx >> 1, mode = bx & 1;
  const int t = threadIdx.x, w = t >> 6, lane = t & 63;
  const int quad = lane >> 4, ln = lane & 15;
  const int wrow = (w >> 1) * 64, wcol = (w & 1) * 64;
  const ushort* Ag = (mode ? ccb : xre) + (size_t)c * (128 * KPAD);
  const ushort* Bg = ccb + (size_t)c * (128 * KPAD);

  f32x4 acc[4][4];
  for (int i = 0; i < 4; ++i)
    for (int j = 0; j < 4; ++j) acc[i][j] = f32x4{0.f, 0.f, 0.f, 0.f};

  // staging addressing: instruction s covers chunks ci = 128w+64s+lane
  const int ci0 = 128 * w;
  const int row0 = (ci0 + lane) >> 2;
  const int row1 = (ci0 + 64 + lane) >> 2;
  const int q0 = (lane & 3) ^ (row0 & 3);
  const int q1 = (lane & 3) ^ (row1 & 3);
  const ushort* ga0 = Ag + (size_t)row0 * KPAD + q0 * 8;
  const ushort* ga1 = Ag + (size_t)row1 * KPAD + q1 * 8;
  const ushort* gb0 = Bg + (size_t)row0 * KPAD + q0 * 8;
  const ushort* gb1 = Bg + (size_t)row1 * KPAD + q1 * 8;
  const int la0 = ci0 * 8, la1 = (ci0 + 64) * 8;

#define ISSUE(k, p)                                                          \
  do {                                                                       \
    int kb = (k) * 32;                                                       \
    __builtin_amdgcn_global_load_lds(                                        \
        (const __attribute__((address_space(1))) unsigned int*)(ga0 + kb),   \
        (__attribute__((address_space(3))) unsigned int*)&At[p][la0], 16, 0, 0); \
    __builtin_amdgcn_global_load_lds(                                        \
        (const __attribute__((address_space(1))) unsigned int*)(ga1 + kb),   \
        (__attribute__((address_space(3))) unsigned int*)&At[p][la1], 16, 0, 0); \
    if (!mode) {                                                             \
      __builtin_amdgcn_global_load_lds(                                      \
          (const __attribute__((address_space(1))) unsigned int*)(gb0 + kb), \
          (__attribute__((address_space(3))) unsigned int*)&Bt[p][la0], 16, 0, 0); \
      __builtin_amdgcn_global_load_lds(                                      \
          (const __attribute__((address_space(1))) unsigned int*)(gb1 + kb), \
          (__attribute__((address_space(3))) unsigned int*)&Bt[p][la1], 16, 0, 0); \
    }                                                                        \
  } while (0)

  ISSUE(0, 0);
  for (int k0 = 0; k0 < 25; ++k0) {
    __syncthreads();
    if (k0 < 24) ISSUE(k0 + 1, (k0 + 1) & 1);
    const ushort* Ab = At[k0 & 1];
    const ushort* Bb = mode ? At[k0 & 1] : Bt[k0 & 1];
    bf16x8 af[4], bf[4];
    for (int i = 0; i < 4; ++i) {
      int m = wrow + i * 16 + ln;
      af[i] = *(const bf16x8*)&Ab[(m * 4 + (quad ^ (m & 3))) * 8];
    }
    for (int j = 0; j < 4; ++j) {
      int n = wcol + j * 16 + ln;
      bf[j] = *(const bf16x8*)&Bb[(n * 4 + (quad ^ (n & 3))) * 8];
    }
    for (int i = 0; i < 4; ++i)
      for (int j = 0; j < 4; ++j)
        acc[i][j] = __builtin_amdgcn_mfma_f32_16x16x32_bf16(af[i], bf[j], acc[i][j], 0, 0, 0);
  }
#undef ISSUE

  // epilogue: d = sqrt(max(|a|^2+|b|^2-2ab, 1e-12))
  const float* rn = (mode ? bnorm : anorm) + c * 128;
  const float* cn = bnorm + c * 128;
  float cnv[4];
  for (int j = 0; j < 4; ++j) cnv[j] = cn[wcol + j * 16 + ln];
  float d[4][4][4];  // [i][j][reg]
  for (int i = 0; i < 4; ++i) {
    float rv[4];
    for (int r = 0; r < 4; ++r) rv[r] = rn[wrow + i * 16 + quad * 4 + r];
    for (int j = 0; j < 4; ++j)
      for (int r = 0; r < 4; ++r) {
        float d2 = rv[r] + cnv[j] - 2.f * acc[i][j][r];
        d[i][j][r] = sqrtf(fmaxf(d2, 1e-12f));
      }
  }

  if (mode) {
    float* ob = out_c + (size_t)c * (128 * 128);
    for (int i = 0; i < 4; ++i)
      for (int r = 0; r < 4; ++r) {
        int m = wrow + i * 16 + quad * 4 + r;
        for (int j = 0; j < 4; ++j) ob[m * 128 + wcol + j * 16 + ln] = d[i][j][r];
      }
  } else {
    int half = w & 1;
    for (int i = 0; i < 4; ++i)
      for (int r = 0; r < 4; ++r) {
        int m = wrow + i * 16 + quad * 4 + r;
        size_t ob = ((size_t)m * 256 + c) * 128 + wcol;
        for (int j = 0; j < 4; ++j) out_d[ob + j * 16 + ln] = d[i][j][r];
        float mn = fminf(fminf(d[i][0][r], d[i][1][r]), fminf(d[i][2][r], d[i][3][r]));
        for (int off = 1; off < 16; off <<= 1) mn = fminf(mn, __shfl_xor(mn, off, 64));
        if (ln == 0) smin[half][m] = mn;
      }
    __syncthreads();
    for (int i = 0; i < 4; ++i)
      for (int r = 0; r < 4; ++r) {
        int m = wrow + i * 16 + quad * 4 + r;
        float mn = fminf(smin[0][m], smin[1][m]);
        float s = 0.f;
        for (int j = 0; j < 4; ++j) {
          float e = __expf(-32.f * (d[i][j][r] - mn));
          d[i][j][r] = e;
          s += e;
        }
        for (int off = 1; off < 16; off <<= 1) s += __shfl_xor(s, off, 64);
        if (ln == 0) ssum[half][m] = s;
      }
    __syncthreads();
    for (int i = 0; i < 4; ++i)
      for (int r = 0; r < 4; ++r) {
        int m = wrow + i * 16 + quad * 4 + r;
        float inv = 1.f / (ssum[0][m] + ssum[1][m]);
        size_t ob = ((size_t)m * 256 + c) * 128 + wcol;
        for (int j = 0; j < 4; ++j) out_s[ob + j * 16 + ln] = d[i][j][r] * inv;
      }
  }
}

extern "C" void kernel_launch(void* const* d_in, const int* in_sizes, int n_in,
                              void* d_out, int out_size, void* d_ws, size_t ws_size,
                              hipStream_t stream) {
  const float* x   = (const float*)d_in[0];
  const float* lnw = (const float*)d_in[1];
  const float* lnb = (const float*)d_in[2];
  const float* cc  = (const float*)d_in[3];
  float* out   = (float*)d_out;
  float* out_d = out;             // x_distance        [8,16,256,128]
  float* out_s = out + 4194304;   // x_distance_assign [8,16,256,128]
  float* out_c = out + 8388608;   // cluster_dist      [256,128,128]

  ushort* xre_b = (ushort*)d_ws;            // 256*128*800 bf16 = 52.4 MB
  ushort* cc_b  = xre_b + 26214400;         // 52.4 MB
  float*  anorm = (float*)(cc_b + 26214400);  // 256*128 fp32
  float*  bnorm = anorm + 32768;

  hipMemsetAsync(anorm, 0, 32768 * sizeof(float), stream);
  ln_transpose_kernel<<<dim3(25, 128), 256, 0, stream>>>(x, lnw, lnb, xre_b, anorm);
  cc_convert_kernel<<<2048, 256, 0, stream>>>(cc, cc_b, bnorm);
  gemm_mfma_kernel<<<512, 256, 0, stream>>>(xre_b, cc_b, anorm, bnorm,
                                            out_d, out_s, out_c);
}

// Round 6
// 315.310 us; speedup vs baseline: 1.0147x; 1.0147x over previous
//
#include <hip/hip_runtime.h>
#include <hip/hip_bf16.h>
#include <math.h>

// Problem constants
#define C_DIM 256
#define BD    128   // B*D
#define HW    784   // H*W = K
#define CN    128
#define KPAD  832   // 26 k-tiles of 32; rows = 1664 B = 13 x 128 B (line-aligned)
#define KTILES 26

typedef short bf16x8 __attribute__((ext_vector_type(8)));
typedef float f32x4 __attribute__((ext_vector_type(4)));

// fp32 -> bf16 RNE
__device__ inline ushort f2b(float f) {
  unsigned u = __float_as_uint(f);
  unsigned r = (u + 0x7FFFu + ((u >> 16) & 1u)) >> 16;
  return (ushort)r;
}

// ---------------------------------------------------------------------------
// K1: LayerNorm over C + transpose -> bf16 x_re [C][BD][KPAD] + row norms.
// grid (13, 128), block 256. Quad-row: each 16-lane quad owns one hw row,
// parallel sum/sumsq 4-step quad shuffle. hw-tile 64 (block 12: 16 rows +
// 48 zero-pad). LDS [c][64] ushort, column-swizzled r' = r ^ ((c>>2)&12)
// (keeps write conflicts 4-way, preserves 4-ushort contiguity).
// Write-out: uint2/lane -> 128 B line-aligned per channel (KPAD=832).
// ---------------------------------------------------------------------------
__global__ __launch_bounds__(256) void ln_transpose_kernel(
    const float* __restrict__ x, const float* __restrict__ lnw,
    const float* __restrict__ lnb, ushort* __restrict__ xre,
    float* __restrict__ anorm) {
  __shared__ ushort btile[256 * 64];   // 32 KB, swizzled columns
  __shared__ float nbuf[4][256];
  const int t = threadIdx.x, bd = blockIdx.y, bx = blockIdx.x;
  const int hw0 = bx * 64;
  const int w = t >> 6, lane = t & 63;
  const int q = lane >> 4, l = lane & 15;
  const bool last = (bx == 12);
  const int ngroups = last ? 1 : 4;
  const int rpw = ngroups * 4;
  if (last) {  // zero rows 16..63 (hw 784..831); swizzle region is closed
    for (int r = 16; r < 64; r += 4)
      *(ushort4*)&btile[t * 64 + r] = make_ushort4(0, 0, 0, 0);
  }
  float4 wv[4], bv[4];
  for (int s = 0; s < 4; ++s) {
    wv[s] = *(const float4*)(lnw + s * 64 + l * 4);
    bv[s] = *(const float4*)(lnb + s * 64 + l * 4);
  }
  float nrm[4][4];
  for (int s = 0; s < 4; ++s)
    for (int j = 0; j < 4; ++j) nrm[s][j] = 0.f;
  const float* xb = x + ((size_t)bd * HW + hw0) * 256 + l * 4;
  const int xr = l & 12;               // (c>>2)&12 for c = s*64 + l*4 + j
  for (int g = 0; g < ngroups; ++g) {
    int r = w * rpw + g * 4 + q;       // block-local row
    float4 v[4];
    for (int s = 0; s < 4; ++s)
      v[s] = *(const float4*)(xb + (size_t)r * 256 + s * 64);
    float sum = 0.f, sq = 0.f;
    for (int s = 0; s < 4; ++s) {
      sum += v[s].x + v[s].y + v[s].z + v[s].w;
      sq = fmaf(v[s].x, v[s].x, sq); sq = fmaf(v[s].y, v[s].y, sq);
      sq = fmaf(v[s].z, v[s].z, sq); sq = fmaf(v[s].w, v[s].w, sq);
    }
    for (int off = 1; off <= 8; off <<= 1) {
      sum += __shfl_xor(sum, off, 64);
      sq  += __shfl_xor(sq, off, 64);
    }
    float mu = sum * (1.f / 256.f);
    float var = fmaf(-mu, mu, sq * (1.f / 256.f));
    float sc = rsqrtf(var + 1e-5f);
    int rp = r ^ xr;
    for (int s = 0; s < 4; ++s) {
      float y0 = (v[s].x - mu) * sc * wv[s].x + bv[s].x;
      float y1 = (v[s].y - mu) * sc * wv[s].y + bv[s].y;
      float y2 = (v[s].z - mu) * sc * wv[s].z + bv[s].z;
      float y3 = (v[s].w - mu) * sc * wv[s].w + bv[s].w;
      nrm[s][0] = fmaf(y0, y0, nrm[s][0]);
      nrm[s][1] = fmaf(y1, y1, nrm[s][1]);
      nrm[s][2] = fmaf(y2, y2, nrm[s][2]);
      nrm[s][3] = fmaf(y3, y3, nrm[s][3]);
      int c = s * 64 + l * 4;
      btile[(c + 0) * 64 + rp] = f2b(y0);
      btile[(c + 1) * 64 + rp] = f2b(y1);
      btile[(c + 2) * 64 + rp] = f2b(y2);
      btile[(c + 3) * 64 + rp] = f2b(y3);
    }
  }
  // reduce norms over the 4 quads, q==0 publishes
  for (int s = 0; s < 4; ++s)
    for (int j = 0; j < 4; ++j) {
      float v = nrm[s][j];
      v += __shfl_xor(v, 16, 64);
      v += __shfl_xor(v, 32, 64);
      nrm[s][j] = v;
    }
  if (q == 0)
    for (int s = 0; s < 4; ++s)
      for (int j = 0; j < 4; ++j) nbuf[w][s * 64 + l * 4 + j] = nrm[s][j];
  __syncthreads();
  float tot = nbuf[0][t] + nbuf[1][t] + nbuf[2][t] + nbuf[3][t];
  atomicAdd(&anorm[t * 128 + bd], tot);  // anorm[c][bd]
  // write-out: uint2/lane; 4 channels x 128 B aligned per instruction
  for (int i = 0; i < 16; ++i) {
    int c = w * 64 + i * 4 + (lane >> 4);
    int xw = (w * 16 + i) & 12;          // (c>>2)&12
    int ho = (lane & 15) * 4;
    uint2 val = *(const uint2*)&btile[c * 64 + (ho ^ xw)];
    *(uint2*)(xre + (size_t)c * (BD * KPAD) + (size_t)bd * KPAD + hw0 + ho) = val;
  }
}

// ---------------------------------------------------------------------------
// K2: cc fp32 -> bf16 [C][CN][KPAD] + fp32 row norms + zero K-pad.
// grid 2048, block 256. Quad-row; 4-step quad shuffle for the norm.
// ---------------------------------------------------------------------------
__global__ __launch_bounds__(256) void cc_convert_kernel(
    const float* __restrict__ cc, ushort* __restrict__ ccb,
    float* __restrict__ bnorm) {
  int b = blockIdx.x, c = b >> 3;
  int t = threadIdx.x, w = t >> 6, lane = t & 63;
  int q = lane >> 4, l = lane & 15;
  int r = (b & 7) * 16 + w * 4 + q;
  const float4* src = (const float4*)(cc + ((size_t)c * CN + r) * HW);
  ushort* dst = ccb + ((size_t)c * CN + r) * KPAD;
  float nrm = 0.f;
  for (int i = 0; i < 13; ++i) {
    int f = i * 16 + l;
    if (f < 196) {
      float4 v = src[f];
      nrm = fmaf(v.x, v.x, nrm); nrm = fmaf(v.y, v.y, nrm);
      nrm = fmaf(v.z, v.z, nrm); nrm = fmaf(v.w, v.w, nrm);
      ushort4 o; o.x = f2b(v.x); o.y = f2b(v.y); o.z = f2b(v.z); o.w = f2b(v.w);
      *(ushort4*)(dst + f * 4) = o;
    }
  }
  for (int off = 1; off <= 8; off <<= 1) nrm += __shfl_xor(nrm, off, 64);
  if (l == 0) bnorm[c * 128 + r] = nrm;
  if (l < 12) *(ushort4*)(dst + 784 + l * 4) = make_ushort4(0, 0, 0, 0);  // 784..831
}

// ---------------------------------------------------------------------------
// K3: MFMA GEMM-dist. grid 1024: c = bx>>2, mode = (bx>>1)&1, nh = bx&1.
// Tile 128 rows x 64 cols (cols nh*64..+64), BK=32, 26 k-tiles.
// mode1 (cc vs cc): B-slab is rows nh*64..+64 of the A-tile -> no B staging.
// Double-buffered, issue-after-barrier. Softmax deferred to K4.
// ---------------------------------------------------------------------------
__global__ __launch_bounds__(256, 4) void gemm_mfma_kernel(
    const ushort* __restrict__ xre, const ushort* __restrict__ ccb,
    const float* __restrict__ anorm, const float* __restrict__ bnorm,
    float* __restrict__ out_d, float* __restrict__ out_c) {
  __shared__ __align__(16) ushort At[2][4096];  // 128 x 32
  __shared__ __align__(16) ushort Bt[2][2048];  // 64 x 32 (mode0 only)
  const int bx = blockIdx.x;
  const int c = bx >> 2, mode = (bx >> 1) & 1, nh = bx & 1;
  const int t = threadIdx.x, w = t >> 6, lane = t & 63;
  const int quad = lane >> 4, ln = lane & 15;
  const ushort* Ag = (mode ? ccb : xre) + (size_t)c * (128 * KPAD);
  const ushort* Bg = ccb + (size_t)c * (128 * KPAD) + (size_t)(nh * 64) * KPAD;

  f32x4 acc[2][4];
  for (int i = 0; i < 2; ++i)
    for (int j = 0; j < 4; ++j) acc[i][j] = f32x4{0.f, 0.f, 0.f, 0.f};

  // A: slots ci = w*128 + s*64 + lane hold global chunk (row=ci>>2, q=(ci&3)^(row&3))
  const int ciA0 = w * 128 + lane, ciA1 = ciA0 + 64;
  const int rowA0 = ciA0 >> 2, rowA1 = ciA1 >> 2;
  const int qA0 = (ciA0 & 3) ^ (rowA0 & 3), qA1 = (ciA1 & 3) ^ (rowA1 & 3);
  const ushort* gA0 = Ag + (size_t)rowA0 * KPAD + qA0 * 8;
  const ushort* gA1 = Ag + (size_t)rowA1 * KPAD + qA1 * 8;
  // B: slot ci = t
  const int rowB = t >> 2, qB = (t & 3) ^ (rowB & 3);
  const ushort* gB = Bg + (size_t)rowB * KPAD + qB * 8;

#define ISSUE(k, p)                                                            \
  do {                                                                         \
    int kb = (k) * 32;                                                         \
    __builtin_amdgcn_global_load_lds(                                          \
        (const __attribute__((address_space(1))) unsigned int*)(gA0 + kb),     \
        (__attribute__((address_space(3))) unsigned int*)&At[p][ciA0 * 8], 16, 0, 0); \
    __builtin_amdgcn_global_load_lds(                                          \
        (const __attribute__((address_space(1))) unsigned int*)(gA1 + kb),     \
        (__attribute__((address_space(3))) unsigned int*)&At[p][ciA1 * 8], 16, 0, 0); \
    if (!mode)                                                                 \
      __builtin_amdgcn_global_load_lds(                                        \
          (const __attribute__((address_space(1))) unsigned int*)(gB + kb),    \
          (__attribute__((address_space(3))) unsigned int*)&Bt[p][t * 8], 16, 0, 0); \
  } while (0)

  ISSUE(0, 0);
  for (int k0 = 0; k0 < KTILES; ++k0) {
    __syncthreads();
    if (k0 < KTILES - 1) ISSUE(k0 + 1, (k0 + 1) & 1);
    const int p = k0 & 1;
    const ushort* Ab = At[p];
    bf16x8 af[2], bf[4];
    for (int i = 0; i < 2; ++i) {
      int m = w * 32 + i * 16 + ln;
      af[i] = *(const bf16x8*)&Ab[(m * 4 + (quad ^ (m & 3))) * 8];
    }
    for (int j = 0; j < 4; ++j) {
      int n = j * 16 + ln;
      if (mode) {
        int mr = nh * 64 + n;
        bf[j] = *(const bf16x8*)&Ab[(mr * 4 + (quad ^ (mr & 3))) * 8];
      } else {
        bf[j] = *(const bf16x8*)&Bt[p][(n * 4 + (quad ^ (n & 3))) * 8];
      }
    }
    for (int i = 0; i < 2; ++i)
      for (int j = 0; j < 4; ++j)
        acc[i][j] = __builtin_amdgcn_mfma_f32_16x16x32_bf16(af[i], bf[j], acc[i][j], 0, 0, 0);
  }
#undef ISSUE

  // epilogue: d = sqrt(max(|a|^2+|b|^2-2ab, 1e-12))
  const float* rn = (mode ? bnorm : anorm) + c * 128;
  const float* cnp = bnorm + c * 128 + nh * 64;
  float cnv[4];
  for (int j = 0; j < 4; ++j) cnv[j] = cnp[j * 16 + ln];
  for (int i = 0; i < 2; ++i) {
    float rv[4];
    for (int r = 0; r < 4; ++r) rv[r] = rn[w * 32 + i * 16 + quad * 4 + r];
    for (int r = 0; r < 4; ++r) {
      int m = w * 32 + i * 16 + quad * 4 + r;
      float dr[4];
      for (int j = 0; j < 4; ++j) {
        float d2 = rv[r] + cnv[j] - 2.f * acc[i][j][r];
        dr[j] = sqrtf(fmaxf(d2, 1e-12f));
      }
      if (mode) {
        float* ob = out_c + (size_t)c * (128 * 128) + (size_t)m * 128 + nh * 64;
        for (int j = 0; j < 4; ++j) ob[j * 16 + ln] = dr[j];
      } else {
        float* ob = out_d + ((size_t)m * 256 + c) * 128 + nh * 64;
        for (int j = 0; j < 4; ++j) ob[j * 16 + ln] = dr[j];
      }
    }
  }
}

// ---------------------------------------------------------------------------
// K4: row softmax(-32*d) over the 128-col rows of out_d -> out_s.
// grid 2048, block 256; each quad owns one row (8 floats/lane).
// ---------------------------------------------------------------------------
__global__ __launch_bounds__(256) void softmax_kernel(
    const float* __restrict__ out_d, float* __restrict__ out_s) {
  const int t = threadIdx.x, w = t >> 6, lane = t & 63;
  const int q = lane >> 4, l = lane & 15;
  const int row = blockIdx.x * 16 + w * 4 + q;
  const float4* src = (const float4*)(out_d + (size_t)row * 128);
  float4 v0 = src[l], v1 = src[l + 16];
  float mn = fminf(fminf(fminf(v0.x, v0.y), fminf(v0.z, v0.w)),
                   fminf(fminf(v1.x, v1.y), fminf(v1.z, v1.w)));
  for (int off = 1; off <= 8; off <<= 1) mn = fminf(mn, __shfl_xor(mn, off, 64));
  float e[8];
  e[0] = __expf(-32.f * (v0.x - mn)); e[1] = __expf(-32.f * (v0.y - mn));
  e[2] = __expf(-32.f * (v0.z - mn)); e[3] = __expf(-32.f * (v0.w - mn));
  e[4] = __expf(-32.f * (v1.x - mn)); e[5] = __expf(-32.f * (v1.y - mn));
  e[6] = __expf(-32.f * (v1.z - mn)); e[7] = __expf(-32.f * (v1.w - mn));
  float s = e[0] + e[1] + e[2] + e[3] + e[4] + e[5] + e[6] + e[7];
  for (int off = 1; off <= 8; off <<= 1) s += __shfl_xor(s, off, 64);
  float inv = 1.f / s;
  float4* dst = (float4*)(out_s + (size_t)row * 128);
  dst[l]      = make_float4(e[0] * inv, e[1] * inv, e[2] * inv, e[3] * inv);
  dst[l + 16] = make_float4(e[4] * inv, e[5] * inv, e[6] * inv, e[7] * inv);
}

extern "C" void kernel_launch(void* const* d_in, const int* in_sizes, int n_in,
                              void* d_out, int out_size, void* d_ws, size_t ws_size,
                              hipStream_t stream) {
  const float* x   = (const float*)d_in[0];
  const float* lnw = (const float*)d_in[1];
  const float* lnb = (const float*)d_in[2];
  const float* cc  = (const float*)d_in[3];
  float* out   = (float*)d_out;
  float* out_d = out;             // x_distance        [8,16,256,128]
  float* out_s = out + 4194304;   // x_distance_assign [8,16,256,128]
  float* out_c = out + 8388608;   // cluster_dist      [256,128,128]

  ushort* xre_b = (ushort*)d_ws;              // 256*128*832 bf16 = 54.5 MB
  ushort* cc_b  = xre_b + 27262976;           // 54.5 MB
  float*  anorm = (float*)(cc_b + 27262976);  // 256*128 fp32
  float*  bnorm = anorm + 32768;

  hipMemsetAsync(anorm, 0, 32768 * sizeof(float), stream);
  ln_transpose_kernel<<<dim3(13, 128), 256, 0, stream>>>(x, lnw, lnb, xre_b, anorm);
  cc_convert_kernel<<<2048, 256, 0, stream>>>(cc, cc_b, bnorm);
  gemm_mfma_kernel<<<1024, 256, 0, stream>>>(xre_b, cc_b, anorm, bnorm, out_d, out_c);
  softmax_kernel<<<2048, 256, 0, stream>>>(out_d, out_s);
}